// Round 5
// baseline (253.251 us; speedup 1.0000x reference)
//
#include <hip/hip_runtime.h>
#include <hip/hip_bf16.h>
#include <cmath>
#include <cstring>

#define B_TOT 16384
#define NSTEPS_PAD 192

typedef unsigned int uint_t;
typedef unsigned short ushort_t;
typedef __attribute__((ext_vector_type(8))) short bf16x8;
typedef __attribute__((ext_vector_type(16))) float f32x16;

// workspace layout (bytes); total 1837056 (< 2228224 proven available)
#define WS_TAB 0          // uint32[192]
#define WS_CSQ 1024       // double[64]
#define WS_S   2048       // float[64][4096] = 1 MiB
#define WS_PPK 1050624    // A-packs: 192 steps * 4 KiB = 786432
// pack frag addr: ((s*4 + mt*2 + plane)*64 + lane)*16 ; plane 0=hi 1=lo
// lane (r=lane&31,h=lane>>5) holds P[n=mt*32+r][kappa = s*16 + h*8 + e]

// ---------- prep 1: S[n][cell] = sum_k cq[n,k]*gamma[k][cell] (LDS-staged) ----
__global__ __launch_bounds__(256) void prep_s(const float* __restrict__ g,
                                              const float* __restrict__ cq,
                                              char* __restrict__ ws) {
  __shared__ float gl[128][68];   // gamma[k][J*64 .. +64), padded
  __shared__ float cql[16][132];  // cq rows for this block's 16 n
  float* S = (float*)(ws + WS_S);
  const int ns = blockIdx.x >> 6, J = blockIdx.x & 63, t = threadIdx.x;
  for (int i = t; i < 2048; i += 256) {  // 128 k * 16 float4
    const int k = i >> 4, c4 = (i & 15) * 4;
    *(float4*)&gl[k][c4] = *(const float4*)(g + (size_t)k * 4096 + J * 64 + c4);
  }
  for (int i = t; i < 2048; i += 256) {
    const int n16 = i >> 7, k = i & 127;
    cql[n16][k] = cq[(ns * 16 + n16) * 128 + k];
  }
  __syncthreads();
  const int n16 = t >> 4, c4 = (t & 15) * 4;
  float4 acc = {0.f, 0.f, 0.f, 0.f};
#pragma unroll 8
  for (int k = 0; k < 128; ++k) {
    const float w = cql[n16][k];
    const float4 gv = *(const float4*)&gl[k][c4];
    acc.x = fmaf(w, gv.x, acc.x);
    acc.y = fmaf(w, gv.y, acc.y);
    acc.z = fmaf(w, gv.z, acc.z);
    acc.w = fmaf(w, gv.w, acc.w);
  }
  *(float4*)(S + (size_t)(ns * 16 + n16) * 4096 + J * 64 + c4) = acc;
}

// ---------- prep 2: build bf16 hi/lo A-packs + tab + csq (256 blocks) --------
__global__ __launch_bounds__(256) void prep_pack(
    const float* __restrict__ qfw, const float* __restrict__ cq,
    const float* __restrict__ qzw, const float* __restrict__ qzb,
    const float* __restrict__ qfb, char* __restrict__ ws) {
  __shared__ float Sl[4096];
  __shared__ uint_t tabl[192];
  __shared__ float psumf[128][2];
  const int n = blockIdx.x & 63, part = blockIdx.x >> 6, t = threadIdx.x;
  const float* __restrict__ S = (const float*)(ws + WS_S) + (size_t)n * 4096;
  for (int i = t; i < 4096; i += 256) Sl[i] = S[i];
  if (t < 64) {
    const int i = t;
    const int start = (i < 16) ? 4 * i
                     : (i < 32) ? 64 + 3 * (i - 16)
                     : (i < 48) ? 112 + 2 * (i - 32)
                                : 144 + (i - 48);
    const int nst = 4 - (i >> 4);
    for (int u = 0; u < nst; ++u)
      tabl[start + u] = (0u << 16) | ((uint_t)i << 8) | (uint_t)(16 * ((i >> 4) + u));
  } else if (t < 80) tabl[160 + (t - 64)] = (1u << 16) | (uint_t)((t - 64) * 16);
  else if (t < 84)   tabl[176 + (t - 80)] = (2u << 16) | (uint_t)((t - 80) * 16);
  else if (t == 84)  tabl[180] = (3u << 16);
  else if (t < 96)   tabl[181 + (t - 85)] = 0;
  __syncthreads();
  if (part == 0 && n == 0 && t < 192) ((uint_t*)(ws + WS_TAB))[t] = tabl[t];

  const int mt = n >> 5, r = n & 31;
  auto wpack = [&](int s, int jo, float val) {
    const __hip_bfloat16 hb = __float2bfloat16(val);
    const float hf = __bfloat162float(hb);
    const __hip_bfloat16 lb = __float2bfloat16(val - hf);
    ushort_t hu, lu;
    memcpy(&hu, &hb, 2);
    memcpy(&lu, &lb, 2);
    const size_t base =
        (((size_t)s * 4 + mt * 2) * 64 + ((jo >> 3) & 1) * 32 + r) * 16 + (jo & 7) * 2;
    *(ushort_t*)(ws + WS_PPK + base) = hu;
    *(ushort_t*)(ws + WS_PPK + base + 1024) = lu;
  };

  // Z2 region: 2560 values, split 640/part
  for (int v = part * 640 + t; v < (part + 1) * 640; v += 256) {
    const int s = v >> 4, jo = v & 15;
    const uint_t inf = tabl[s];
    const int i = (inf >> 8) & 255, j0 = inf & 255;
    const int j = j0 + jo;
    const float val =
        (j < i) ? 0.f : ((j > i) ? Sl[i * 64 + j] + Sl[j * 64 + i] : Sl[i * 64 + i]);
    wpack(s, jo, val);
  }
  const float* __restrict__ cqn = cq + n * 128;

  if (part >= 2) {
    // feat region: M[n][f], f in [(part-2)*128, +128), 2 threads per f
    const int fl = t & 127, kh = t >> 7;
    const int f = (part - 2) * 128 + fl;
    float a = 0.f;
#pragma unroll 8
    for (int k = 0; k < 64; ++k)
      a = fmaf(qfw[(kh * 64 + k) * 256 + f], cqn[kh * 64 + k], a);
    psumf[fl][kh] = a;
    __syncthreads();
    if (t < 128) {
      const int ff = (part - 2) * 128 + t;
      wpack(160 + (ff >> 4), ff & 15, psumf[t][0] + psumf[t][1]);
    }
  } else if (part == 1) {
    // z region: W2[n][i]
    if (t < 64) {
      float a = 0.f;
#pragma unroll 8
      for (int k = 0; k < 128; ++k) a = fmaf(cqn[k], qzw[k * 64 + t], a);
      wpack(176 + (t >> 4), t & 15, a);
    }
    // zero-pad steps 181..191
    for (int v2 = t; v2 < 176; v2 += 256) wpack(181 + (v2 >> 4), v2 & 15, 0.f);
  } else {
    // part 0: const region + csq
    if (t == 128) {
      float a = 0.f;
      for (int k = 0; k < 128; ++k) a = fmaf(qzb[k] + qfb[k], cqn[k], a);
      wpack(180, 0, a);
    } else if (t > 128 && t < 144) wpack(180, t - 128, 0.f);
    if (t == 144) {
      double a = 0.0;
      for (int d = 0; d < 64; ++d) a = fma((double)cqn[d], (double)cqn[d], a);
      ((double*)(ws + WS_CSQ))[n] = a;
    }
  }
}

// ---------- fused main kernel (1024 threads = 16 waves, 64 rows/block) -------
__global__ __launch_bounds__(1024) void fused_kernel(
    const float* __restrict__ z, const float* __restrict__ feat,
    const float* __restrict__ cq, const char* __restrict__ ws,
    float* __restrict__ out) {
  __shared__ __align__(16) unsigned char smem[48384];
  float (*z_lds)[68] = (float (*)[68])(smem);            // 17408
  float (*s_lin)[65] = (float (*)[65])(smem + 17408);    // 16640 -> 34048
  double (*s_lds)[65] = (double (*)[65])(smem);          // overlay [0, 33280)
  double (*pmax)[17] = (double (*)[17])(smem + 34048);   // 8704 -> 42752 (also psum)
  int (*parg)[17] = (int (*)[17])(smem + 42752);         // 4352 -> 47104
  double* rowmax = (double*)(smem + 47104);              // 512
  int* rowarg = (int*)(smem + 47616);                    // 256
  double* sum_lds = (double*)(smem + 47872);             // 512 -> 48384

  const int t = threadIdx.x, lane = t & 63;
  const int wv = __builtin_amdgcn_readfirstlane(t >> 6);  // 0..15
  const int b0 = blockIdx.x * 64;
  const int h = lane >> 5, c = lane & 31;

  // stage z (cols 64..67 zeroed) + zero s_lin
  for (int i = t; i < 4096; i += 1024) z_lds[i >> 6][i & 63] = z[(size_t)b0 * 64 + i];
  if (t < 256) z_lds[t >> 2][64 + (t & 3)] = 0.f;
  for (int i = t; i < 64 * 65; i += 1024) ((float*)s_lin)[i] = 0.f;
  __syncthreads();

  // ---- single GEMM: s_lin[b][n] = q[b]·cq_n  (K-split by 16 waves) ----
  const bf16x8* __restrict__ pp = (const bf16x8*)(ws + WS_PPK);
  const uint_t* __restrict__ tab = (const uint_t*)(ws + WS_TAB);
  f32x16 acc[2][2] = {};
#pragma unroll 1
  for (int it = 0; it < 12; ++it) {  // fixed trip count, s < 192
    const int s = wv + it * 16;
    const uint_t inf = tab[s];
    const int mode = inf >> 16, i_idx = (inf >> 8) & 255, p0 = inf & 255;
    const bf16x8 Ah0 = pp[((size_t)s * 4 + 0) * 64 + lane];
    const bf16x8 Al0 = pp[((size_t)s * 4 + 1) * 64 + lane];
    const bf16x8 Ah1 = pp[((size_t)s * 4 + 2) * 64 + lane];
    const bf16x8 Al1 = pp[((size_t)s * 4 + 3) * 64 + lane];
#pragma unroll
    for (int nt = 0; nt < 2; ++nt) {
      const int bl = nt * 32 + c;
      float xv[8];
      if (mode == 0) {
        const float zi = z_lds[bl][i_idx];
        const float* __restrict__ zp = &z_lds[bl][p0 + h * 8];
        const float4 a = *(const float4*)zp, b2 = *(const float4*)(zp + 4);
        xv[0] = zi * a.x; xv[1] = zi * a.y; xv[2] = zi * a.z; xv[3] = zi * a.w;
        xv[4] = zi * b2.x; xv[5] = zi * b2.y; xv[6] = zi * b2.z; xv[7] = zi * b2.w;
      } else if (mode == 1) {
        const float* __restrict__ fp = feat + (size_t)(b0 + bl) * 256 + p0 + h * 8;
        const float4 a = *(const float4*)fp, b2 = *(const float4*)(fp + 4);
        xv[0] = a.x; xv[1] = a.y; xv[2] = a.z; xv[3] = a.w;
        xv[4] = b2.x; xv[5] = b2.y; xv[6] = b2.z; xv[7] = b2.w;
      } else if (mode == 2) {
        const float* __restrict__ zp = &z_lds[bl][p0 + h * 8];
        const float4 a = *(const float4*)zp, b2 = *(const float4*)(zp + 4);
        xv[0] = a.x; xv[1] = a.y; xv[2] = a.z; xv[3] = a.w;
        xv[4] = b2.x; xv[5] = b2.y; xv[6] = b2.z; xv[7] = b2.w;
      } else {
        xv[0] = (h == 0) ? 1.f : 0.f;
        xv[1] = xv[2] = xv[3] = xv[4] = xv[5] = xv[6] = xv[7] = 0.f;
      }
      // RNE hi/lo split
      uint_t bhw[4], blw[4];
#pragma unroll
      for (int e2 = 0; e2 < 4; ++e2) {
        const float2 xp = {xv[2 * e2], xv[2 * e2 + 1]};
        const __hip_bfloat162 hb2 = __float22bfloat162_rn(xp);
        uint_t hw;
        memcpy(&hw, &hb2, 4);
        const float h0 = __uint_as_float(hw << 16);
        const float h1 = __uint_as_float(hw & 0xffff0000u);
        const float2 lp = {xp.x - h0, xp.y - h1};
        const __hip_bfloat162 lb2 = __float22bfloat162_rn(lp);
        uint_t lw;
        memcpy(&lw, &lb2, 4);
        bhw[e2] = hw;
        blw[e2] = lw;
      }
      bf16x8 Bh, Bl;
      memcpy(&Bh, bhw, 16);
      memcpy(&Bl, blw, 16);
      acc[0][nt] = __builtin_amdgcn_mfma_f32_32x32x16_bf16(Ah0, Bh, acc[0][nt], 0, 0, 0);
      acc[0][nt] = __builtin_amdgcn_mfma_f32_32x32x16_bf16(Ah0, Bl, acc[0][nt], 0, 0, 0);
      acc[0][nt] = __builtin_amdgcn_mfma_f32_32x32x16_bf16(Al0, Bh, acc[0][nt], 0, 0, 0);
      acc[1][nt] = __builtin_amdgcn_mfma_f32_32x32x16_bf16(Ah1, Bh, acc[1][nt], 0, 0, 0);
      acc[1][nt] = __builtin_amdgcn_mfma_f32_32x32x16_bf16(Ah1, Bl, acc[1][nt], 0, 0, 0);
      acc[1][nt] = __builtin_amdgcn_mfma_f32_32x32x16_bf16(Al1, Bh, acc[1][nt], 0, 0, 0);
    }
  }
  // fold K-split partials: C layout col=lane&31, row=(r&3)+8*(r>>2)+4*h
#pragma unroll
  for (int mt = 0; mt < 2; ++mt)
#pragma unroll
    for (int nt = 0; nt < 2; ++nt)
#pragma unroll
      for (int r = 0; r < 16; ++r) {
        const int n = mt * 32 + (r & 3) + 8 * (r >> 2) + 4 * h;
        atomicAdd(&s_lin[nt * 32 + c][n], acc[mt][nt][r]);
      }
  __syncthreads();

  // ---- tail: fp64 hyperbolic part; row = lane, n = wv + 16u ----
  float lin[4];
#pragma unroll
  for (int u = 0; u < 4; ++u) lin[u] = s_lin[lane][wv + 16 * u];
  float zr[64];
  {
    const float4* __restrict__ zg = (const float4*)(z + (size_t)(b0 + lane) * 64);
#pragma unroll
    for (int j = 0; j < 16; ++j) {
      const float4 v = zg[j];
      zr[4 * j] = v.x; zr[4 * j + 1] = v.y; zr[4 * j + 2] = v.z; zr[4 * j + 3] = v.w;
    }
  }
  double z_sq;
  {
    double a0 = 0.0, a1 = 0.0;
#pragma unroll
    for (int i = 0; i < 64; i += 2) {
      a0 = fma((double)zr[i], (double)zr[i], a0);
      a1 = fma((double)zr[i + 1], (double)zr[i + 1], a1);
    }
    z_sq = a0 + a1;
  }
  const double EPS = 0.001;
  const double SQRTK = sqrt(128.0);
  double tau = SQRTK * fmax(1.0 - z_sq, 0.001) * 0.5;
  tau = fmax(tau, 0.01);
  const double inv_tau = 1.0 / tau;
  const double r2 = fmin(z_sq, 1.0 - EPS);
  const double lam_fac = (1.0 - r2 + EPS) * 0.5 / SQRTK;  // == (1/lam)/sqrt(K)
  const double* __restrict__ csqd = (const double*)(ws + WS_CSQ);

  double sc[4];
#pragma unroll
  for (int u = 0; u < 4; ++u) {
    const int n = wv + 16 * u;
    const float* __restrict__ cqn = cq + n * 128;  // wave-uniform -> s_load
    double zc0 = 0.0, zc1 = 0.0;
#pragma unroll
    for (int i = 0; i < 64; i += 2) {
      zc0 = fma((double)zr[i], (double)cqn[i], zc0);
      zc1 = fma((double)zr[i + 1], (double)cqn[i + 1], zc1);
    }
    const double c_sq = csqd[n];
    const double dist_sq = z_sq + c_sq - 2.0 * (zc0 + zc1);
    const double denom = (1.0 - z_sq) * (1.0 - c_sq);
    double arg = 1.0 + 2.0 * dist_sq / (denom + EPS);
    arg = fmax(arg, 1.0 + EPS);
    const double dist = log(arg + sqrt(arg * arg - 1.0));
    sc[u] = -dist * inv_tau + (double)lin[u] * lam_fac;
  }
  __syncthreads();  // all z_lds / s_lin reads complete before s_lds overlay

  // ---- parallel softmax/argmax; scores stay in registers ----
  {
    double mx = sc[0];
    int am = wv;
#pragma unroll
    for (int u = 1; u < 4; ++u)
      if (sc[u] > mx) { mx = sc[u]; am = wv + 16 * u; }
#pragma unroll
    for (int u = 0; u < 4; ++u) s_lds[lane][wv + 16 * u] = sc[u];
    pmax[lane][wv] = mx;
    parg[lane][wv] = am;
  }
  __syncthreads();
  if (t < 64) {
    double m = pmax[t][0];
    int a = parg[t][0];
#pragma unroll
    for (int g = 1; g < 16; ++g) {
      const double v = pmax[t][g];
      const int aa = parg[t][g];
      if (v > m || (v == m && aa < a)) { m = v; a = aa; }
    }
    rowmax[t] = m;
    rowarg[t] = a;
  }
  __syncthreads();
  {
    const double m = rowmax[lane];
    double ps = 0.0;
#pragma unroll
    for (int u = 0; u < 4; ++u) {
      const double e = exp(sc[u] - m);
      s_lds[lane][wv + 16 * u] = e;
      ps += e;
    }
    pmax[lane][wv] = ps;  // psum reuse (rowmax already extracted)
  }
  __syncthreads();
  if (t < 64) {
    double s = 0.0;
#pragma unroll
    for (int g = 0; g < 16; ++g) s += pmax[t][g];
    sum_lds[t] = 1.0 / s;
  }
  __syncthreads();
  for (int idx = t; idx < 4096; idx += 1024) {
    const int b = idx >> 6, n = idx & 63;
    out[(size_t)(b0 + b) * 64 + n] = (float)(s_lds[b][n] * sum_lds[b]);
  }
  if (t < 64) out[(size_t)B_TOT * 64 + b0 + t] = (float)rowarg[t];
}

extern "C" void kernel_launch(void* const* d_in, const int* in_sizes, int n_in,
                              void* d_out, int out_size, void* d_ws, size_t ws_size,
                              hipStream_t stream) {
  const float* z = (const float*)d_in[0];
  const float* feat = (const float*)d_in[1];
  const float* qzw = (const float*)d_in[2];
  const float* qzb = (const float*)d_in[3];
  const float* qfw = (const float*)d_in[4];
  const float* qfb = (const float*)d_in[5];
  const float* gamma = (const float*)d_in[6];
  const float* cq = (const float*)d_in[7];
  float* out = (float*)d_out;
  char* ws = (char*)d_ws;

  prep_s<<<dim3(256), dim3(256), 0, stream>>>(gamma, cq, ws);
  prep_pack<<<dim3(256), dim3(256), 0, stream>>>(qfw, cq, qzw, qzb, qfb, ws);
  fused_kernel<<<dim3(B_TOT / 64), dim3(1024), 0, stream>>>(z, feat, cq, ws, out);
}

// Round 6
// 207.503 us; speedup vs baseline: 1.2205x; 1.2205x over previous
//
#include <hip/hip_runtime.h>
#include <hip/hip_bf16.h>
#include <cmath>
#include <cstring>

#define B_TOT 16384
#define NSTEPS_PAD 192

typedef unsigned int uint_t;
typedef unsigned short ushort_t;
typedef __attribute__((ext_vector_type(8))) short bf16x8;
typedef __attribute__((ext_vector_type(16))) float f32x16;

// workspace layout (bytes); total 1837056
#define WS_TAB 0          // uint32[192]
#define WS_CSQ 1024       // double[64]
#define WS_S   2048       // float[64][4096] = 1 MiB
#define WS_PPK 1050624    // A-packs: 192 steps * 4 KiB = 786432
// pack frag addr: ((s*4 + mt*2 + plane)*64 + lane)*16 ; plane 0=hi 1=lo
// lane (r=lane&31,h=lane>>5) holds P[n=mt*32+r][kappa = s*16 + h*8 + e]

// ---------- prep 1: S[n][cell] = sum_k cq[n,k]*gamma[k][cell] (LDS-staged) ----
__global__ __launch_bounds__(256) void prep_s(const float* __restrict__ g,
                                              const float* __restrict__ cq,
                                              char* __restrict__ ws) {
  __shared__ float gl[128][68];
  __shared__ float cql[16][132];
  float* S = (float*)(ws + WS_S);
  const int ns = blockIdx.x >> 6, J = blockIdx.x & 63, t = threadIdx.x;
  for (int i = t; i < 2048; i += 256) {
    const int k = i >> 4, c4 = (i & 15) * 4;
    *(float4*)&gl[k][c4] = *(const float4*)(g + (size_t)k * 4096 + J * 64 + c4);
  }
  for (int i = t; i < 2048; i += 256) {
    const int n16 = i >> 7, k = i & 127;
    cql[n16][k] = cq[(ns * 16 + n16) * 128 + k];
  }
  __syncthreads();
  const int n16 = t >> 4, c4 = (t & 15) * 4;
  float4 acc = {0.f, 0.f, 0.f, 0.f};
#pragma unroll 8
  for (int k = 0; k < 128; ++k) {
    const float w = cql[n16][k];
    const float4 gv = *(const float4*)&gl[k][c4];
    acc.x = fmaf(w, gv.x, acc.x);
    acc.y = fmaf(w, gv.y, acc.y);
    acc.z = fmaf(w, gv.z, acc.z);
    acc.w = fmaf(w, gv.w, acc.w);
  }
  *(float4*)(S + (size_t)(ns * 16 + n16) * 4096 + J * 64 + c4) = acc;
}

// ---------- prep 2: build bf16 hi/lo A-packs + tab + csq (256 blocks) --------
__global__ __launch_bounds__(256) void prep_pack(
    const float* __restrict__ qfw, const float* __restrict__ cq,
    const float* __restrict__ qzw, const float* __restrict__ qzb,
    const float* __restrict__ qfb, char* __restrict__ ws) {
  __shared__ float Sl[4096];
  __shared__ uint_t tabl[192];
  __shared__ float psumf[128][2];
  const int n = blockIdx.x & 63, part = blockIdx.x >> 6, t = threadIdx.x;
  const float* __restrict__ S = (const float*)(ws + WS_S) + (size_t)n * 4096;
  for (int i = t; i < 4096; i += 256) Sl[i] = S[i];
  if (t < 64) {
    const int i = t;
    const int start = (i < 16) ? 4 * i
                     : (i < 32) ? 64 + 3 * (i - 16)
                     : (i < 48) ? 112 + 2 * (i - 32)
                                : 144 + (i - 48);
    const int nst = 4 - (i >> 4);
    for (int u = 0; u < nst; ++u)
      tabl[start + u] = (0u << 16) | ((uint_t)i << 8) | (uint_t)(16 * ((i >> 4) + u));
  } else if (t < 80) tabl[160 + (t - 64)] = (1u << 16) | (uint_t)((t - 64) * 16);
  else if (t < 84)   tabl[176 + (t - 80)] = (2u << 16) | (uint_t)((t - 80) * 16);
  else if (t == 84)  tabl[180] = (3u << 16);
  else if (t < 96)   tabl[181 + (t - 85)] = 0;
  __syncthreads();
  if (part == 0 && n == 0 && t < 192) ((uint_t*)(ws + WS_TAB))[t] = tabl[t];

  const int mt = n >> 5, r = n & 31;
  auto wpack = [&](int s, int jo, float val) {
    const __hip_bfloat16 hb = __float2bfloat16(val);
    const float hf = __bfloat162float(hb);
    const __hip_bfloat16 lb = __float2bfloat16(val - hf);
    ushort_t hu, lu;
    memcpy(&hu, &hb, 2);
    memcpy(&lu, &lb, 2);
    const size_t base =
        (((size_t)s * 4 + mt * 2) * 64 + ((jo >> 3) & 1) * 32 + r) * 16 + (jo & 7) * 2;
    *(ushort_t*)(ws + WS_PPK + base) = hu;
    *(ushort_t*)(ws + WS_PPK + base + 1024) = lu;
  };

  for (int v = part * 640 + t; v < (part + 1) * 640; v += 256) {
    const int s = v >> 4, jo = v & 15;
    const uint_t inf = tabl[s];
    const int i = (inf >> 8) & 255, j0 = inf & 255;
    const int j = j0 + jo;
    const float val =
        (j < i) ? 0.f : ((j > i) ? Sl[i * 64 + j] + Sl[j * 64 + i] : Sl[i * 64 + i]);
    wpack(s, jo, val);
  }
  const float* __restrict__ cqn = cq + n * 128;

  if (part >= 2) {
    const int fl = t & 127, kh = t >> 7;
    const int f = (part - 2) * 128 + fl;
    float a = 0.f;
#pragma unroll 8
    for (int k = 0; k < 64; ++k)
      a = fmaf(qfw[(kh * 64 + k) * 256 + f], cqn[kh * 64 + k], a);
    psumf[fl][kh] = a;
    __syncthreads();
    if (t < 128) {
      const int ff = (part - 2) * 128 + t;
      wpack(160 + (ff >> 4), ff & 15, psumf[t][0] + psumf[t][1]);
    }
  } else if (part == 1) {
    if (t < 64) {
      float a = 0.f;
#pragma unroll 8
      for (int k = 0; k < 128; ++k) a = fmaf(cqn[k], qzw[k * 64 + t], a);
      wpack(176 + (t >> 4), t & 15, a);
    }
    for (int v2 = t; v2 < 176; v2 += 256) wpack(181 + (v2 >> 4), v2 & 15, 0.f);
  } else {
    if (t == 128) {
      float a = 0.f;
      for (int k = 0; k < 128; ++k) a = fmaf(qzb[k] + qfb[k], cqn[k], a);
      wpack(180, 0, a);
    } else if (t > 128 && t < 144) wpack(180, t - 128, 0.f);
    if (t == 144) {
      double a = 0.0;
      for (int d = 0; d < 64; ++d) a = fma((double)cqn[d], (double)cqn[d], a);
      ((double*)(ws + WS_CSQ))[n] = a;
    }
  }
}

// ---------- fused main kernel (1024 threads = 16 waves, 64 rows/block) -------
// __launch_bounds__(1024, 4): 4 waves/EU min -> 128-VGPR cap (R4 proved ~100
// VGPRs suffice for this GEMM). R5's implicit 64-VGPR cap caused scratch
// spills (FETCH 77MB / WRITE 107MB).
__global__ __launch_bounds__(1024, 4) void fused_kernel(
    const float* __restrict__ z, const float* __restrict__ feat,
    const float* __restrict__ cq, const char* __restrict__ ws,
    float* __restrict__ out) {
  __shared__ __align__(16) unsigned char smem[50944];
  float (*z_lds)[68] = (float (*)[68])(smem);            // 17408 (GEMM B source)
  float (*s_lin)[65] = (float (*)[65])(smem + 17408);    // 16640 -> 34048
  float (*zt)[66] = (float (*)[66])(smem + 34048);       // 16896 -> 50944 (tail)
  double (*s_lds)[65] = (double (*)[65])(smem);          // overlay [0, 33280)
  double (*pmax)[17] = (double (*)[17])(smem + 34048);   // overlay zt: 8704
  int (*parg)[17] = (int (*)[17])(smem + 42752);         // 4352 -> 47104
  double* rowmax = (double*)(smem + 47104);              // 512
  int* rowarg = (int*)(smem + 47616);                    // 256
  double* sum_lds = (double*)(smem + 47872);             // 512 -> 48384

  const int t = threadIdx.x, lane = t & 63;
  const int wv = __builtin_amdgcn_readfirstlane(t >> 6);  // 0..15
  const int b0 = blockIdx.x * 64;
  const int h = lane >> 5, c = lane & 31;

  // stage z (row-major for GEMM, transposed for tail) + zero s_lin
  for (int i = t; i < 4096; i += 1024) {
    const float v = z[(size_t)b0 * 64 + i];
    z_lds[i >> 6][i & 63] = v;
    zt[i & 63][i >> 6] = v;
  }
  if (t < 256) z_lds[t >> 2][64 + (t & 3)] = 0.f;
  for (int i = t; i < 64 * 65; i += 1024) ((float*)s_lin)[i] = 0.f;
  __syncthreads();

  // ---- single GEMM: s_lin[b][n] = q[b]·cq_n  (K-split by 16 waves) ----
  const bf16x8* __restrict__ pp = (const bf16x8*)(ws + WS_PPK);
  const uint_t* __restrict__ tab = (const uint_t*)(ws + WS_TAB);
  f32x16 acc[2][2] = {};
#pragma unroll 1
  for (int it = 0; it < 12; ++it) {  // fixed trip count, s < 192
    const int s = wv + it * 16;
    const uint_t inf = tab[s];
    const int mode = inf >> 16, i_idx = (inf >> 8) & 255, p0 = inf & 255;
    const bf16x8 Ah0 = pp[((size_t)s * 4 + 0) * 64 + lane];
    const bf16x8 Al0 = pp[((size_t)s * 4 + 1) * 64 + lane];
    const bf16x8 Ah1 = pp[((size_t)s * 4 + 2) * 64 + lane];
    const bf16x8 Al1 = pp[((size_t)s * 4 + 3) * 64 + lane];
#pragma unroll
    for (int nt = 0; nt < 2; ++nt) {
      const int bl = nt * 32 + c;
      float xv[8];
      if (mode == 0) {
        const float zi = z_lds[bl][i_idx];
        const float* __restrict__ zp = &z_lds[bl][p0 + h * 8];
        const float4 a = *(const float4*)zp, b2 = *(const float4*)(zp + 4);
        xv[0] = zi * a.x; xv[1] = zi * a.y; xv[2] = zi * a.z; xv[3] = zi * a.w;
        xv[4] = zi * b2.x; xv[5] = zi * b2.y; xv[6] = zi * b2.z; xv[7] = zi * b2.w;
      } else if (mode == 1) {
        const float* __restrict__ fp = feat + (size_t)(b0 + bl) * 256 + p0 + h * 8;
        const float4 a = *(const float4*)fp, b2 = *(const float4*)(fp + 4);
        xv[0] = a.x; xv[1] = a.y; xv[2] = a.z; xv[3] = a.w;
        xv[4] = b2.x; xv[5] = b2.y; xv[6] = b2.z; xv[7] = b2.w;
      } else if (mode == 2) {
        const float* __restrict__ zp = &z_lds[bl][p0 + h * 8];
        const float4 a = *(const float4*)zp, b2 = *(const float4*)(zp + 4);
        xv[0] = a.x; xv[1] = a.y; xv[2] = a.z; xv[3] = a.w;
        xv[4] = b2.x; xv[5] = b2.y; xv[6] = b2.z; xv[7] = b2.w;
      } else {
        xv[0] = (h == 0) ? 1.f : 0.f;
        xv[1] = xv[2] = xv[3] = xv[4] = xv[5] = xv[6] = xv[7] = 0.f;
      }
      // RNE hi/lo split
      uint_t bhw[4], blw[4];
#pragma unroll
      for (int e2 = 0; e2 < 4; ++e2) {
        const float2 xp = {xv[2 * e2], xv[2 * e2 + 1]};
        const __hip_bfloat162 hb2 = __float22bfloat162_rn(xp);
        uint_t hw;
        memcpy(&hw, &hb2, 4);
        const float h0 = __uint_as_float(hw << 16);
        const float h1 = __uint_as_float(hw & 0xffff0000u);
        const float2 lp = {xp.x - h0, xp.y - h1};
        const __hip_bfloat162 lb2 = __float22bfloat162_rn(lp);
        uint_t lw;
        memcpy(&lw, &lb2, 4);
        bhw[e2] = hw;
        blw[e2] = lw;
      }
      bf16x8 Bh, Bl;
      memcpy(&Bh, bhw, 16);
      memcpy(&Bl, blw, 16);
      acc[0][nt] = __builtin_amdgcn_mfma_f32_32x32x16_bf16(Ah0, Bh, acc[0][nt], 0, 0, 0);
      acc[0][nt] = __builtin_amdgcn_mfma_f32_32x32x16_bf16(Ah0, Bl, acc[0][nt], 0, 0, 0);
      acc[0][nt] = __builtin_amdgcn_mfma_f32_32x32x16_bf16(Al0, Bh, acc[0][nt], 0, 0, 0);
      acc[1][nt] = __builtin_amdgcn_mfma_f32_32x32x16_bf16(Ah1, Bh, acc[1][nt], 0, 0, 0);
      acc[1][nt] = __builtin_amdgcn_mfma_f32_32x32x16_bf16(Ah1, Bl, acc[1][nt], 0, 0, 0);
      acc[1][nt] = __builtin_amdgcn_mfma_f32_32x32x16_bf16(Al1, Bh, acc[1][nt], 0, 0, 0);
    }
  }
  // fold K-split partials: C layout col=lane&31, row=(r&3)+8*(r>>2)+4*h
#pragma unroll
  for (int mt = 0; mt < 2; ++mt)
#pragma unroll
    for (int nt = 0; nt < 2; ++nt)
#pragma unroll
      for (int r = 0; r < 16; ++r) {
        const int n = mt * 32 + (r & 3) + 8 * (r >> 2) + 4 * h;
        atomicAdd(&s_lin[nt * 32 + c][n], acc[mt][nt][r]);
      }
  __syncthreads();

  // ---- tail: fp64 hyperbolic part; row = lane, n = wv + 16u ----
  float lin[4];
#pragma unroll
  for (int u = 0; u < 4; ++u) lin[u] = s_lin[lane][wv + 16 * u];

  // one pass over i: z_sq + 4 z·cq dots; zt reads are bank-conflict-free,
  // cq reads wave-uniform (scalar). 5 independent fp64 chains for ILP.
  double z_sq = 0.0, zc[4] = {0.0, 0.0, 0.0, 0.0};
  {
    const float* __restrict__ c0 = cq + (wv + 0) * 128;
    const float* __restrict__ c1 = cq + (wv + 16) * 128;
    const float* __restrict__ c2 = cq + (wv + 32) * 128;
    const float* __restrict__ c3 = cq + (wv + 48) * 128;
#pragma unroll 8
    for (int i = 0; i < 64; ++i) {
      const double zv = (double)zt[i][lane];
      z_sq = fma(zv, zv, z_sq);
      zc[0] = fma(zv, (double)c0[i], zc[0]);
      zc[1] = fma(zv, (double)c1[i], zc[1]);
      zc[2] = fma(zv, (double)c2[i], zc[2]);
      zc[3] = fma(zv, (double)c3[i], zc[3]);
    }
  }
  const double EPS = 0.001;
  const double SQRTK = sqrt(128.0);
  double tau = SQRTK * fmax(1.0 - z_sq, 0.001) * 0.5;
  tau = fmax(tau, 0.01);
  const double inv_tau = 1.0 / tau;
  const double r2 = fmin(z_sq, 1.0 - EPS);
  const double lam_fac = (1.0 - r2 + EPS) * 0.5 / SQRTK;  // == (1/lam)/sqrt(K)
  const double* __restrict__ csqd = (const double*)(ws + WS_CSQ);

  double sc[4];
#pragma unroll
  for (int u = 0; u < 4; ++u) {
    const int n = wv + 16 * u;
    const double c_sq = csqd[n];
    const double dist_sq = z_sq + c_sq - 2.0 * zc[u];
    const double denom = (1.0 - z_sq) * (1.0 - c_sq);
    double arg = 1.0 + 2.0 * dist_sq / (denom + EPS);
    arg = fmax(arg, 1.0 + EPS);
    const double dist = log(arg + sqrt(arg * arg - 1.0));
    sc[u] = -dist * inv_tau + (double)lin[u] * lam_fac;
  }
  __syncthreads();  // all s_lin / zt reads complete before overlay writes

  // ---- parallel softmax/argmax; scores stay in registers ----
  {
    double mx = sc[0];
    int am = wv;
#pragma unroll
    for (int u = 1; u < 4; ++u)
      if (sc[u] > mx) { mx = sc[u]; am = wv + 16 * u; }
#pragma unroll
    for (int u = 0; u < 4; ++u) s_lds[lane][wv + 16 * u] = sc[u];
    pmax[lane][wv] = mx;
    parg[lane][wv] = am;
  }
  __syncthreads();
  if (t < 64) {
    double m = pmax[t][0];
    int a = parg[t][0];
#pragma unroll
    for (int g = 1; g < 16; ++g) {
      const double v = pmax[t][g];
      const int aa = parg[t][g];
      if (v > m || (v == m && aa < a)) { m = v; a = aa; }
    }
    rowmax[t] = m;
    rowarg[t] = a;
  }
  __syncthreads();
  {
    const double m = rowmax[lane];
    double ps = 0.0;
#pragma unroll
    for (int u = 0; u < 4; ++u) {
      const double e = exp(sc[u] - m);
      s_lds[lane][wv + 16 * u] = e;
      ps += e;
    }
    pmax[lane][wv] = ps;  // psum reuse (rowmax already extracted)
  }
  __syncthreads();
  if (t < 64) {
    double s = 0.0;
#pragma unroll
    for (int g = 0; g < 16; ++g) s += pmax[t][g];
    sum_lds[t] = 1.0 / s;
  }
  __syncthreads();
  for (int idx = t; idx < 4096; idx += 1024) {
    const int b = idx >> 6, n = idx & 63;
    out[(size_t)(b0 + b) * 64 + n] = (float)(s_lds[b][n] * sum_lds[b]);
  }
  if (t < 64) out[(size_t)B_TOT * 64 + b0 + t] = (float)rowarg[t];
}

extern "C" void kernel_launch(void* const* d_in, const int* in_sizes, int n_in,
                              void* d_out, int out_size, void* d_ws, size_t ws_size,
                              hipStream_t stream) {
  const float* z = (const float*)d_in[0];
  const float* feat = (const float*)d_in[1];
  const float* qzw = (const float*)d_in[2];
  const float* qzb = (const float*)d_in[3];
  const float* qfw = (const float*)d_in[4];
  const float* qfb = (const float*)d_in[5];
  const float* gamma = (const float*)d_in[6];
  const float* cq = (const float*)d_in[7];
  float* out = (float*)d_out;
  char* ws = (char*)d_ws;

  prep_s<<<dim3(256), dim3(256), 0, stream>>>(gamma, cq, ws);
  prep_pack<<<dim3(256), dim3(256), 0, stream>>>(qfw, cq, qzw, qzb, qfb, ws);
  fused_kernel<<<dim3(B_TOT / 64), dim3(1024), 0, stream>>>(z, feat, cq, ws, out);
}

// Round 7
// 170.474 us; speedup vs baseline: 1.4856x; 1.2172x over previous
//
#include <hip/hip_runtime.h>
#include <hip/hip_bf16.h>
#include <cmath>
#include <cstring>

#define B_TOT 16384
#define NSTEPS_PAD 192

typedef unsigned int uint_t;
typedef unsigned short ushort_t;
typedef __attribute__((ext_vector_type(8))) short bf16x8;
typedef __attribute__((ext_vector_type(16))) float f32x16;

// workspace layout (bytes); total 1837056
#define WS_TAB 0          // uint32[192]
#define WS_CSQ 1024       // double[64]
#define WS_S   2048       // float[64][4096] = 1 MiB
#define WS_PPK 1050624    // A-packs: 192 steps * 4 KiB = 786432
// pack frag addr: ((s*4 + mt*2 + plane)*64 + lane)*16 ; plane 0=hi 1=lo
// lane (r=lane&31,h=lane>>5) holds P[n=mt*32+r][kappa = s*16 + h*8 + e]

// ---------- prep 1: S[n][cell] = sum_k cq[n,k]*gamma[k][cell] (LDS-staged) ----
__global__ __launch_bounds__(256) void prep_s(const float* __restrict__ g,
                                              const float* __restrict__ cq,
                                              char* __restrict__ ws) {
  __shared__ float gl[128][68];
  __shared__ float cql[16][132];
  float* S = (float*)(ws + WS_S);
  const int ns = blockIdx.x >> 6, J = blockIdx.x & 63, t = threadIdx.x;
  for (int i = t; i < 2048; i += 256) {
    const int k = i >> 4, c4 = (i & 15) * 4;
    *(float4*)&gl[k][c4] = *(const float4*)(g + (size_t)k * 4096 + J * 64 + c4);
  }
  for (int i = t; i < 2048; i += 256) {
    const int n16 = i >> 7, k = i & 127;
    cql[n16][k] = cq[(ns * 16 + n16) * 128 + k];
  }
  __syncthreads();
  const int n16 = t >> 4, c4 = (t & 15) * 4;
  float4 acc = {0.f, 0.f, 0.f, 0.f};
#pragma unroll 8
  for (int k = 0; k < 128; ++k) {
    const float w = cql[n16][k];
    const float4 gv = *(const float4*)&gl[k][c4];
    acc.x = fmaf(w, gv.x, acc.x);
    acc.y = fmaf(w, gv.y, acc.y);
    acc.z = fmaf(w, gv.z, acc.z);
    acc.w = fmaf(w, gv.w, acc.w);
  }
  *(float4*)(S + (size_t)(ns * 16 + n16) * 4096 + J * 64 + c4) = acc;
}

// ---------- prep 2: build bf16 hi/lo A-packs + tab + csq (256 blocks) --------
__global__ __launch_bounds__(256) void prep_pack(
    const float* __restrict__ qfw, const float* __restrict__ cq,
    const float* __restrict__ qzw, const float* __restrict__ qzb,
    const float* __restrict__ qfb, char* __restrict__ ws) {
  __shared__ float Sl[4096];
  __shared__ uint_t tabl[192];
  __shared__ float psumf[128][2];
  const int n = blockIdx.x & 63, part = blockIdx.x >> 6, t = threadIdx.x;
  const float* __restrict__ S = (const float*)(ws + WS_S) + (size_t)n * 4096;
  for (int i = t; i < 4096; i += 256) Sl[i] = S[i];
  if (t < 64) {
    const int i = t;
    const int start = (i < 16) ? 4 * i
                     : (i < 32) ? 64 + 3 * (i - 16)
                     : (i < 48) ? 112 + 2 * (i - 32)
                                : 144 + (i - 48);
    const int nst = 4 - (i >> 4);
    for (int u = 0; u < nst; ++u)
      tabl[start + u] = (0u << 16) | ((uint_t)i << 8) | (uint_t)(16 * ((i >> 4) + u));
  } else if (t < 80) tabl[160 + (t - 64)] = (1u << 16) | (uint_t)((t - 64) * 16);
  else if (t < 84)   tabl[176 + (t - 80)] = (2u << 16) | (uint_t)((t - 80) * 16);
  else if (t == 84)  tabl[180] = (3u << 16);
  else if (t < 96)   tabl[181 + (t - 85)] = 0;
  __syncthreads();
  if (part == 0 && n == 0 && t < 192) ((uint_t*)(ws + WS_TAB))[t] = tabl[t];

  const int mt = n >> 5, r = n & 31;
  auto wpack = [&](int s, int jo, float val) {
    const __hip_bfloat16 hb = __float2bfloat16(val);
    const float hf = __bfloat162float(hb);
    const __hip_bfloat16 lb = __float2bfloat16(val - hf);
    ushort_t hu, lu;
    memcpy(&hu, &hb, 2);
    memcpy(&lu, &lb, 2);
    const size_t base =
        (((size_t)s * 4 + mt * 2) * 64 + ((jo >> 3) & 1) * 32 + r) * 16 + (jo & 7) * 2;
    *(ushort_t*)(ws + WS_PPK + base) = hu;
    *(ushort_t*)(ws + WS_PPK + base + 1024) = lu;
  };

  for (int v = part * 640 + t; v < (part + 1) * 640; v += 256) {
    const int s = v >> 4, jo = v & 15;
    const uint_t inf = tabl[s];
    const int i = (inf >> 8) & 255, j0 = inf & 255;
    const int j = j0 + jo;
    const float val =
        (j < i) ? 0.f : ((j > i) ? Sl[i * 64 + j] + Sl[j * 64 + i] : Sl[i * 64 + i]);
    wpack(s, jo, val);
  }
  const float* __restrict__ cqn = cq + n * 128;

  if (part >= 2) {
    const int fl = t & 127, kh = t >> 7;
    const int f = (part - 2) * 128 + fl;
    float a = 0.f;
#pragma unroll 8
    for (int k = 0; k < 64; ++k)
      a = fmaf(qfw[(kh * 64 + k) * 256 + f], cqn[kh * 64 + k], a);
    psumf[fl][kh] = a;
    __syncthreads();
    if (t < 128) {
      const int ff = (part - 2) * 128 + t;
      wpack(160 + (ff >> 4), ff & 15, psumf[t][0] + psumf[t][1]);
    }
  } else if (part == 1) {
    if (t < 64) {
      float a = 0.f;
#pragma unroll 8
      for (int k = 0; k < 128; ++k) a = fmaf(cqn[k], qzw[k * 64 + t], a);
      wpack(176 + (t >> 4), t & 15, a);
    }
    for (int v2 = t; v2 < 176; v2 += 256) wpack(181 + (v2 >> 4), v2 & 15, 0.f);
  } else {
    if (t == 128) {
      float a = 0.f;
      for (int k = 0; k < 128; ++k) a = fmaf(qzb[k] + qfb[k], cqn[k], a);
      wpack(180, 0, a);
    } else if (t > 128 && t < 144) wpack(180, t - 128, 0.f);
    if (t == 144) {
      double a = 0.0;
      for (int d = 0; d < 64; ++d) a = fma((double)cqn[d], (double)cqn[d], a);
      ((double*)(ws + WS_CSQ))[n] = a;
    }
  }
}

// ---------- fused main kernel: 512 blocks x 512 threads, 32 rows/block -------
// 2 independent blocks/CU so one block's GEMM overlaps the other's tail and
// barrier drains. 24-step K-loop (K-split 8) + unroll 2 for load overlap.
// __launch_bounds__(512, 4): 128-VGPR cap (R5 lesson: always pin arg 2).
__global__ __launch_bounds__(512, 4) void fused_kernel(
    const float* __restrict__ z, const float* __restrict__ feat,
    const float* __restrict__ cq, const char* __restrict__ ws,
    float* __restrict__ out) {
  __shared__ __align__(16) unsigned char smem[26880];
  float (*z_lds)[68] = (float (*)[68])(smem);            // 8704 (GEMM B source)
  float (*s_lin)[65] = (float (*)[65])(smem + 8704);     // 8320 -> 17024
  float (*zt)[36] = (float (*)[36])(smem + 17024);       // 9216 -> 26240 (tail)
  double (*s_lds)[65] = (double (*)[65])(smem);          // overlay [0, 16640)
  double (*pmax)[17] = (double (*)[17])(smem + 17024);   // overlay zt: 4352
  int (*parg)[17] = (int (*)[17])(smem + 21376);         // 2176 -> 23552
  double* rowmax = (double*)(smem + 23552);              // 256
  int* rowarg = (int*)(smem + 23808);                    // 128 -> 23936
  double* sum_lds = (double*)(smem + 24064);             // 256 -> 24320

  const int t = threadIdx.x, lane = t & 63;
  const int wv = __builtin_amdgcn_readfirstlane(t >> 6);  // 0..7
  const int b0 = blockIdx.x * 32;
  const int h = lane >> 5, c = lane & 31;

  // stage z (row-major for GEMM + transposed for tail) + zero s_lin
  for (int i = t; i < 2048; i += 512) {
    const float v = z[(size_t)b0 * 64 + i];
    z_lds[i >> 6][i & 63] = v;
    zt[i & 63][i >> 6] = v;
  }
  if (t < 128) z_lds[t >> 2][64 + (t & 3)] = 0.f;
  for (int i = t; i < 32 * 65; i += 512) ((float*)s_lin)[i] = 0.f;
  __syncthreads();

  // ---- single GEMM: s_lin[b][n] = q[b]·cq_n  (K-split by 8 waves) ----
  const bf16x8* __restrict__ pp = (const bf16x8*)(ws + WS_PPK);
  const uint_t* __restrict__ tab = (const uint_t*)(ws + WS_TAB);
  f32x16 acc[2] = {};
#pragma unroll 2
  for (int it = 0; it < 24; ++it) {  // fixed trip count, s < 192
    const int s = wv + it * 8;
    const uint_t inf = tab[s];
    const int mode = inf >> 16, i_idx = (inf >> 8) & 255, p0 = inf & 255;
    const bf16x8 Ah0 = pp[((size_t)s * 4 + 0) * 64 + lane];
    const bf16x8 Al0 = pp[((size_t)s * 4 + 1) * 64 + lane];
    const bf16x8 Ah1 = pp[((size_t)s * 4 + 2) * 64 + lane];
    const bf16x8 Al1 = pp[((size_t)s * 4 + 3) * 64 + lane];
    const int bl = c;
    float xv[8];
    if (mode == 0) {
      const float zi = z_lds[bl][i_idx];
      const float* __restrict__ zp = &z_lds[bl][p0 + h * 8];
      const float4 a = *(const float4*)zp, b2 = *(const float4*)(zp + 4);
      xv[0] = zi * a.x; xv[1] = zi * a.y; xv[2] = zi * a.z; xv[3] = zi * a.w;
      xv[4] = zi * b2.x; xv[5] = zi * b2.y; xv[6] = zi * b2.z; xv[7] = zi * b2.w;
    } else if (mode == 1) {
      const float* __restrict__ fp = feat + (size_t)(b0 + bl) * 256 + p0 + h * 8;
      const float4 a = *(const float4*)fp, b2 = *(const float4*)(fp + 4);
      xv[0] = a.x; xv[1] = a.y; xv[2] = a.z; xv[3] = a.w;
      xv[4] = b2.x; xv[5] = b2.y; xv[6] = b2.z; xv[7] = b2.w;
    } else if (mode == 2) {
      const float* __restrict__ zp = &z_lds[bl][p0 + h * 8];
      const float4 a = *(const float4*)zp, b2 = *(const float4*)(zp + 4);
      xv[0] = a.x; xv[1] = a.y; xv[2] = a.z; xv[3] = a.w;
      xv[4] = b2.x; xv[5] = b2.y; xv[6] = b2.z; xv[7] = b2.w;
    } else {
      xv[0] = (h == 0) ? 1.f : 0.f;
      xv[1] = xv[2] = xv[3] = xv[4] = xv[5] = xv[6] = xv[7] = 0.f;
    }
    // RNE hi/lo split
    uint_t bhw[4], blw[4];
#pragma unroll
    for (int e2 = 0; e2 < 4; ++e2) {
      const float2 xp = {xv[2 * e2], xv[2 * e2 + 1]};
      const __hip_bfloat162 hb2 = __float22bfloat162_rn(xp);
      uint_t hw;
      memcpy(&hw, &hb2, 4);
      const float h0 = __uint_as_float(hw << 16);
      const float h1 = __uint_as_float(hw & 0xffff0000u);
      const float2 lp = {xp.x - h0, xp.y - h1};
      const __hip_bfloat162 lb2 = __float22bfloat162_rn(lp);
      uint_t lw;
      memcpy(&lw, &lb2, 4);
      bhw[e2] = hw;
      blw[e2] = lw;
    }
    bf16x8 Bh, Bl;
    memcpy(&Bh, bhw, 16);
    memcpy(&Bl, blw, 16);
    acc[0] = __builtin_amdgcn_mfma_f32_32x32x16_bf16(Ah0, Bh, acc[0], 0, 0, 0);
    acc[0] = __builtin_amdgcn_mfma_f32_32x32x16_bf16(Ah0, Bl, acc[0], 0, 0, 0);
    acc[0] = __builtin_amdgcn_mfma_f32_32x32x16_bf16(Al0, Bh, acc[0], 0, 0, 0);
    acc[1] = __builtin_amdgcn_mfma_f32_32x32x16_bf16(Ah1, Bh, acc[1], 0, 0, 0);
    acc[1] = __builtin_amdgcn_mfma_f32_32x32x16_bf16(Ah1, Bl, acc[1], 0, 0, 0);
    acc[1] = __builtin_amdgcn_mfma_f32_32x32x16_bf16(Al1, Bh, acc[1], 0, 0, 0);
  }
  // fold K-split partials: C layout col=lane&31, row=(r&3)+8*(r>>2)+4*h
#pragma unroll
  for (int mt = 0; mt < 2; ++mt)
#pragma unroll
    for (int r = 0; r < 16; ++r) {
      const int n = mt * 32 + (r & 3) + 8 * (r >> 2) + 4 * h;
      atomicAdd(&s_lin[c][n], acc[mt][r]);
    }
  __syncthreads();

  // ---- tail: fp64 hyperbolic part; row = c, column group cg = wv*2+h ----
  const int cg = wv * 2 + h;  // 0..15; n = cg + 16u
  float lin[4];
#pragma unroll
  for (int u = 0; u < 4; ++u) lin[u] = s_lin[c][cg + 16 * u];

  double z_sq = 0.0, zc[4] = {0.0, 0.0, 0.0, 0.0};
  {
    const float* __restrict__ c0 = cq + (cg + 0) * 128;
    const float* __restrict__ c1 = cq + (cg + 16) * 128;
    const float* __restrict__ c2 = cq + (cg + 32) * 128;
    const float* __restrict__ c3 = cq + (cg + 48) * 128;
#pragma unroll 8
    for (int i = 0; i < 64; ++i) {
      const double zv = (double)zt[i][c];
      z_sq = fma(zv, zv, z_sq);
      zc[0] = fma(zv, (double)c0[i], zc[0]);
      zc[1] = fma(zv, (double)c1[i], zc[1]);
      zc[2] = fma(zv, (double)c2[i], zc[2]);
      zc[3] = fma(zv, (double)c3[i], zc[3]);
    }
  }
  const double EPS = 0.001;
  const double SQRTK = sqrt(128.0);
  double tau = SQRTK * fmax(1.0 - z_sq, 0.001) * 0.5;
  tau = fmax(tau, 0.01);
  const double inv_tau = 1.0 / tau;
  const double r2 = fmin(z_sq, 1.0 - EPS);
  const double lam_fac = (1.0 - r2 + EPS) * 0.5 / SQRTK;  // == (1/lam)/sqrt(K)
  const double* __restrict__ csqd = (const double*)(ws + WS_CSQ);

  double sc[4];
#pragma unroll
  for (int u = 0; u < 4; ++u) {
    const int n = cg + 16 * u;
    const double c_sq = csqd[n];
    const double dist_sq = z_sq + c_sq - 2.0 * zc[u];
    const double denom = (1.0 - z_sq) * (1.0 - c_sq);
    double arg = 1.0 + 2.0 * dist_sq / (denom + EPS);
    arg = fmax(arg, 1.0 + EPS);
    const double dist = log(arg + sqrt(arg * arg - 1.0));
    sc[u] = -dist * inv_tau + (double)lin[u] * lam_fac;
  }
  __syncthreads();  // all s_lin / zt reads complete before overlay writes

  // ---- parallel softmax/argmax; scores stay in registers ----
  {
    double mx = sc[0];
    int am = cg;
#pragma unroll
    for (int u = 1; u < 4; ++u)
      if (sc[u] > mx) { mx = sc[u]; am = cg + 16 * u; }
    pmax[c][cg] = mx;
    parg[c][cg] = am;
  }
  __syncthreads();
  if (t < 32) {
    double m = pmax[t][0];
    int a = parg[t][0];
#pragma unroll
    for (int g = 1; g < 16; ++g) {
      const double v = pmax[t][g];
      const int aa = parg[t][g];
      if (v > m || (v == m && aa < a)) { m = v; a = aa; }
    }
    rowmax[t] = m;
    rowarg[t] = a;
  }
  __syncthreads();
  {
    const double m = rowmax[c];
    double ps = 0.0;
#pragma unroll
    for (int u = 0; u < 4; ++u) {
      const double e = exp(sc[u] - m);
      s_lds[c][cg + 16 * u] = e;
      ps += e;
    }
    pmax[c][cg] = ps;  // psum reuse (rowmax already extracted)
  }
  __syncthreads();
  if (t < 32) {
    double s = 0.0;
#pragma unroll
    for (int g = 0; g < 16; ++g) s += pmax[t][g];
    sum_lds[t] = 1.0 / s;
  }
  __syncthreads();
  for (int idx = t; idx < 2048; idx += 512) {
    const int b = idx >> 6, n = idx & 63;
    out[(size_t)(b0 + b) * 64 + n] = (float)(s_lds[b][n] * sum_lds[b]);
  }
  if (t < 32) out[(size_t)B_TOT * 64 + b0 + t] = (float)rowarg[t];
}

extern "C" void kernel_launch(void* const* d_in, const int* in_sizes, int n_in,
                              void* d_out, int out_size, void* d_ws, size_t ws_size,
                              hipStream_t stream) {
  const float* z = (const float*)d_in[0];
  const float* feat = (const float*)d_in[1];
  const float* qzw = (const float*)d_in[2];
  const float* qzb = (const float*)d_in[3];
  const float* qfw = (const float*)d_in[4];
  const float* qfb = (const float*)d_in[5];
  const float* gamma = (const float*)d_in[6];
  const float* cq = (const float*)d_in[7];
  float* out = (float*)d_out;
  char* ws = (char*)d_ws;

  prep_s<<<dim3(256), dim3(256), 0, stream>>>(gamma, cq, ws);
  prep_pack<<<dim3(256), dim3(256), 0, stream>>>(qfw, cq, qzw, qzb, qfb, ws);
  fused_kernel<<<dim3(B_TOT / 32), dim3(512), 0, stream>>>(z, feat, cq, ws, out);
}

// Round 8
// 158.347 us; speedup vs baseline: 1.5993x; 1.0766x over previous
//
#include <hip/hip_runtime.h>
#include <hip/hip_bf16.h>
#include <cmath>
#include <cstring>

#define B_TOT 16384

typedef unsigned int uint_t;
typedef unsigned short ushort_t;
typedef __attribute__((ext_vector_type(8))) short bf16x8;
typedef __attribute__((ext_vector_type(16))) float f32x16;

// workspace layout (bytes); total 6033408 (~5.76 MiB)
#define WS_TAB 0          // uint32[192]
#define WS_CSQ 1024       // double[64]
#define WS_LIN 4096       // float[16384][64] = 4 MiB (gemm -> tail)
#define WS_S   4198400    // float[64][4096] = 1 MiB (prep_s -> prep_pack)
#define WS_PPK 5246976    // A-packs: 192 steps * 4 KiB = 786432
// pack frag addr: ((s*4 + mt*2 + plane)*64 + lane)*16 ; plane 0=hi 1=lo
// lane (r=lane&31,h=lane>>5) holds P[n=mt*32+r][kappa = s*16 + h*8 + e]

// ---------- prep 1: S[n][cell] = sum_k cq[n,k]*gamma[k][cell] (LDS-staged) ----
__global__ __launch_bounds__(256) void prep_s(const float* __restrict__ g,
                                              const float* __restrict__ cq,
                                              char* __restrict__ ws) {
  __shared__ float gl[128][68];
  __shared__ float cql[16][132];
  float* S = (float*)(ws + WS_S);
  const int ns = blockIdx.x >> 6, J = blockIdx.x & 63, t = threadIdx.x;
  for (int i = t; i < 2048; i += 256) {
    const int k = i >> 4, c4 = (i & 15) * 4;
    *(float4*)&gl[k][c4] = *(const float4*)(g + (size_t)k * 4096 + J * 64 + c4);
  }
  for (int i = t; i < 2048; i += 256) {
    const int n16 = i >> 7, k = i & 127;
    cql[n16][k] = cq[(ns * 16 + n16) * 128 + k];
  }
  __syncthreads();
  const int n16 = t >> 4, c4 = (t & 15) * 4;
  float4 acc = {0.f, 0.f, 0.f, 0.f};
#pragma unroll 8
  for (int k = 0; k < 128; ++k) {
    const float w = cql[n16][k];
    const float4 gv = *(const float4*)&gl[k][c4];
    acc.x = fmaf(w, gv.x, acc.x);
    acc.y = fmaf(w, gv.y, acc.y);
    acc.z = fmaf(w, gv.z, acc.z);
    acc.w = fmaf(w, gv.w, acc.w);
  }
  *(float4*)(S + (size_t)(ns * 16 + n16) * 4096 + J * 64 + c4) = acc;
}

// ---------- prep 2: build bf16 hi/lo A-packs + tab + csq (256 blocks) --------
__global__ __launch_bounds__(256) void prep_pack(
    const float* __restrict__ qfw, const float* __restrict__ cq,
    const float* __restrict__ qzw, const float* __restrict__ qzb,
    const float* __restrict__ qfb, char* __restrict__ ws) {
  __shared__ float Sl[4096];
  __shared__ uint_t tabl[192];
  __shared__ float psumf[128][2];
  const int n = blockIdx.x & 63, part = blockIdx.x >> 6, t = threadIdx.x;
  const float* __restrict__ S = (const float*)(ws + WS_S) + (size_t)n * 4096;
  for (int i = t; i < 4096; i += 256) Sl[i] = S[i];
  if (t < 64) {
    const int i = t;
    const int start = (i < 16) ? 4 * i
                     : (i < 32) ? 64 + 3 * (i - 16)
                     : (i < 48) ? 112 + 2 * (i - 32)
                                : 144 + (i - 48);
    const int nst = 4 - (i >> 4);
    for (int u = 0; u < nst; ++u)
      tabl[start + u] = (0u << 16) | ((uint_t)i << 8) | (uint_t)(16 * ((i >> 4) + u));
  } else if (t < 80) tabl[160 + (t - 64)] = (1u << 16) | (uint_t)((t - 64) * 16);
  else if (t < 84)   tabl[176 + (t - 80)] = (2u << 16) | (uint_t)((t - 80) * 16);
  else if (t == 84)  tabl[180] = (3u << 16);
  else if (t < 96)   tabl[181 + (t - 85)] = 0;
  __syncthreads();
  if (part == 0 && n == 0 && t < 192) ((uint_t*)(ws + WS_TAB))[t] = tabl[t];

  const int mt = n >> 5, r = n & 31;
  auto wpack = [&](int s, int jo, float val) {
    const __hip_bfloat16 hb = __float2bfloat16(val);
    const float hf = __bfloat162float(hb);
    const __hip_bfloat16 lb = __float2bfloat16(val - hf);
    ushort_t hu, lu;
    memcpy(&hu, &hb, 2);
    memcpy(&lu, &lb, 2);
    const size_t base =
        (((size_t)s * 4 + mt * 2) * 64 + ((jo >> 3) & 1) * 32 + r) * 16 + (jo & 7) * 2;
    *(ushort_t*)(ws + WS_PPK + base) = hu;
    *(ushort_t*)(ws + WS_PPK + base + 1024) = lu;
  };

  for (int v = part * 640 + t; v < (part + 1) * 640; v += 256) {
    const int s = v >> 4, jo = v & 15;
    const uint_t inf = tabl[s];
    const int i = (inf >> 8) & 255, j0 = inf & 255;
    const int j = j0 + jo;
    const float val =
        (j < i) ? 0.f : ((j > i) ? Sl[i * 64 + j] + Sl[j * 64 + i] : Sl[i * 64 + i]);
    wpack(s, jo, val);
  }
  const float* __restrict__ cqn = cq + n * 128;

  if (part >= 2) {
    const int fl = t & 127, kh = t >> 7;
    const int f = (part - 2) * 128 + fl;
    float a = 0.f;
#pragma unroll 8
    for (int k = 0; k < 64; ++k)
      a = fmaf(qfw[(kh * 64 + k) * 256 + f], cqn[kh * 64 + k], a);
    psumf[fl][kh] = a;
    __syncthreads();
    if (t < 128) {
      const int ff = (part - 2) * 128 + t;
      wpack(160 + (ff >> 4), ff & 15, psumf[t][0] + psumf[t][1]);
    }
  } else if (part == 1) {
    if (t < 64) {
      float a = 0.f;
#pragma unroll 8
      for (int k = 0; k < 128; ++k) a = fmaf(cqn[k], qzw[k * 64 + t], a);
      wpack(176 + (t >> 4), t & 15, a);
    }
    for (int v2 = t; v2 < 176; v2 += 256) wpack(181 + (v2 >> 4), v2 & 15, 0.f);
  } else {
    if (t == 128) {
      float a = 0.f;
      for (int k = 0; k < 128; ++k) a = fmaf(qzb[k] + qfb[k], cqn[k], a);
      wpack(180, 0, a);
    } else if (t > 128 && t < 144) wpack(180, t - 128, 0.f);
    if (t == 144) {
      double a = 0.0;
      for (int d = 0; d < 64; ++d) a = fma((double)cqn[d], (double)cqn[d], a);
      ((double*)(ws + WS_CSQ))[n] = a;
    }
  }
}

// ---------- GEMM kernel: 512 blocks x 256 thr (4 waves), 32 rows/block ------
// K-split 4 -> 48-step loops (long loops proved best R4 vs R6). Homogeneous
// MFMA phase only; s_lin written to ws for the tail kernel.
// __launch_bounds__(256, 5): 102-VGPR cap, up to 5 blocks/CU.
__global__ __launch_bounds__(256, 5) void gemm_kernel(
    const float* __restrict__ z, const float* __restrict__ feat,
    char* __restrict__ ws) {
  __shared__ __align__(16) unsigned char smem[17024];
  float (*z_lds)[68] = (float (*)[68])(smem);         // 8704
  float (*s_lin)[65] = (float (*)[65])(smem + 8704);  // 8320 -> 17024

  const int t = threadIdx.x, lane = t & 63;
  const int wv = __builtin_amdgcn_readfirstlane(t >> 6);  // 0..3
  const int b0 = blockIdx.x * 32;
  const int h = lane >> 5, c = lane & 31;

  for (int i = t; i < 2048; i += 256) z_lds[i >> 6][i & 63] = z[(size_t)b0 * 64 + i];
  if (t < 128) z_lds[t >> 2][64 + (t & 3)] = 0.f;
  for (int i = t; i < 32 * 65; i += 256) ((float*)s_lin)[i] = 0.f;
  __syncthreads();

  const bf16x8* __restrict__ pp = (const bf16x8*)(ws + WS_PPK);
  const uint_t* __restrict__ tab = (const uint_t*)(ws + WS_TAB);
  f32x16 acc[2] = {};
#pragma unroll 2
  for (int it = 0; it < 48; ++it) {  // s = wv + 4*it covers [0,192)
    const int s = wv + it * 4;
    const uint_t inf = tab[s];
    const int mode = inf >> 16, i_idx = (inf >> 8) & 255, p0 = inf & 255;
    const bf16x8 Ah0 = pp[((size_t)s * 4 + 0) * 64 + lane];
    const bf16x8 Al0 = pp[((size_t)s * 4 + 1) * 64 + lane];
    const bf16x8 Ah1 = pp[((size_t)s * 4 + 2) * 64 + lane];
    const bf16x8 Al1 = pp[((size_t)s * 4 + 3) * 64 + lane];
    const int bl = c;
    float xv[8];
    if (mode == 0) {
      const float zi = z_lds[bl][i_idx];
      const float* __restrict__ zp = &z_lds[bl][p0 + h * 8];
      const float4 a = *(const float4*)zp, b2 = *(const float4*)(zp + 4);
      xv[0] = zi * a.x; xv[1] = zi * a.y; xv[2] = zi * a.z; xv[3] = zi * a.w;
      xv[4] = zi * b2.x; xv[5] = zi * b2.y; xv[6] = zi * b2.z; xv[7] = zi * b2.w;
    } else if (mode == 1) {
      const float* __restrict__ fp = feat + (size_t)(b0 + bl) * 256 + p0 + h * 8;
      const float4 a = *(const float4*)fp, b2 = *(const float4*)(fp + 4);
      xv[0] = a.x; xv[1] = a.y; xv[2] = a.z; xv[3] = a.w;
      xv[4] = b2.x; xv[5] = b2.y; xv[6] = b2.z; xv[7] = b2.w;
    } else if (mode == 2) {
      const float* __restrict__ zp = &z_lds[bl][p0 + h * 8];
      const float4 a = *(const float4*)zp, b2 = *(const float4*)(zp + 4);
      xv[0] = a.x; xv[1] = a.y; xv[2] = a.z; xv[3] = a.w;
      xv[4] = b2.x; xv[5] = b2.y; xv[6] = b2.z; xv[7] = b2.w;
    } else {
      xv[0] = (h == 0) ? 1.f : 0.f;
      xv[1] = xv[2] = xv[3] = xv[4] = xv[5] = xv[6] = xv[7] = 0.f;
    }
    // RNE hi/lo split
    uint_t bhw[4], blw[4];
#pragma unroll
    for (int e2 = 0; e2 < 4; ++e2) {
      const float2 xp = {xv[2 * e2], xv[2 * e2 + 1]};
      const __hip_bfloat162 hb2 = __float22bfloat162_rn(xp);
      uint_t hw;
      memcpy(&hw, &hb2, 4);
      const float h0 = __uint_as_float(hw << 16);
      const float h1 = __uint_as_float(hw & 0xffff0000u);
      const float2 lp = {xp.x - h0, xp.y - h1};
      const __hip_bfloat162 lb2 = __float22bfloat162_rn(lp);
      uint_t lw;
      memcpy(&lw, &lb2, 4);
      bhw[e2] = hw;
      blw[e2] = lw;
    }
    bf16x8 Bh, Bl;
    memcpy(&Bh, bhw, 16);
    memcpy(&Bl, blw, 16);
    acc[0] = __builtin_amdgcn_mfma_f32_32x32x16_bf16(Ah0, Bh, acc[0], 0, 0, 0);
    acc[0] = __builtin_amdgcn_mfma_f32_32x32x16_bf16(Ah0, Bl, acc[0], 0, 0, 0);
    acc[0] = __builtin_amdgcn_mfma_f32_32x32x16_bf16(Al0, Bh, acc[0], 0, 0, 0);
    acc[1] = __builtin_amdgcn_mfma_f32_32x32x16_bf16(Ah1, Bh, acc[1], 0, 0, 0);
    acc[1] = __builtin_amdgcn_mfma_f32_32x32x16_bf16(Ah1, Bl, acc[1], 0, 0, 0);
    acc[1] = __builtin_amdgcn_mfma_f32_32x32x16_bf16(Al1, Bh, acc[1], 0, 0, 0);
  }
  // fold K-split partials: C layout col=lane&31, row=(r&3)+8*(r>>2)+4*h
#pragma unroll
  for (int mt = 0; mt < 2; ++mt)
#pragma unroll
    for (int r = 0; r < 16; ++r) {
      const int n = mt * 32 + (r & 3) + 8 * (r >> 2) + 4 * h;
      atomicAdd(&s_lin[c][n], acc[mt][r]);
    }
  __syncthreads();
  float* __restrict__ gl = (float*)(ws + WS_LIN) + (size_t)b0 * 64;
  for (int i = t; i < 2048; i += 256) gl[i] = s_lin[i >> 6][i & 63];
}

// ---------- tail kernel: 512 blocks x 256 thr, 32 rows/block ----------------
// Pure fp64-VALU phase. zt / s_lin / cq^T all staged in LDS (R7's per-lane
// global cq gathers removed). thread = (row r = t&31, colgroup cg = t>>5);
// n = cg + 8u, u<8.
__global__ __launch_bounds__(256, 4) void tail_kernel(
    const float* __restrict__ z, const float* __restrict__ cq,
    const char* __restrict__ ws, float* __restrict__ out) {
  __shared__ __align__(16) unsigned char smem[37504];
  float (*zt)[33] = (float (*)[33])(smem);               // 8448
  float (*slin)[65] = (float (*)[65])(smem + 8448);      // 8320 -> 16768
  float (*cqT)[65] = (float (*)[65])(smem + 16768);      // 16640 -> 33408
  double (*s_exp)[65] = (double (*)[65])(smem + 16768);  // overlay cqT (16640)
  double (*pmax)[9] = (double (*)[9])(smem + 33408);     // 2304 -> 35712
  int (*parg)[9] = (int (*)[9])(smem + 35712);           // 1152 -> 36864
  double* rowmax = (double*)(smem + 36864);              // 256 -> 37120
  int* rowarg = (int*)(smem + 37120);                    // 128 -> 37248
  double* rowinv = (double*)(smem + 37248);              // 256 -> 37504

  const int t = threadIdx.x;
  const int r = t & 31, cg = t >> 5;
  const int b0 = blockIdx.x * 32;

  for (int i = t; i < 2048; i += 256) zt[i & 63][i >> 6] = z[(size_t)b0 * 64 + i];
  for (int i = t; i < 2048; i += 256)
    slin[i >> 6][i & 63] = ((const float*)(ws + WS_LIN))[(size_t)b0 * 64 + i];
  for (int i = t; i < 4096; i += 256) {
    const int n = i >> 6, ii = i & 63;
    cqT[ii][n] = cq[n * 128 + ii];
  }
  __syncthreads();

  // 9 parallel fp64 chains: z_sq + 8 z.c dots; all LDS reads broadcast or
  // conflict-free (zt stride 33, cqT 2 addrs/wave).
  double z_sq = 0.0, zc[8] = {0.0, 0.0, 0.0, 0.0, 0.0, 0.0, 0.0, 0.0};
#pragma unroll 4
  for (int i = 0; i < 64; ++i) {
    const double zv = (double)zt[i][r];
    z_sq = fma(zv, zv, z_sq);
#pragma unroll
    for (int u = 0; u < 8; ++u)
      zc[u] = fma(zv, (double)cqT[i][cg + 8 * u], zc[u]);
  }
  float lin[8];
#pragma unroll
  for (int u = 0; u < 8; ++u) lin[u] = slin[r][cg + 8 * u];

  const double EPS = 0.001;
  const double SQRTK = sqrt(128.0);
  double tau = SQRTK * fmax(1.0 - z_sq, 0.001) * 0.5;
  tau = fmax(tau, 0.01);
  const double inv_tau = 1.0 / tau;
  const double r2 = fmin(z_sq, 1.0 - EPS);
  const double lam_fac = (1.0 - r2 + EPS) * 0.5 / SQRTK;  // (1/lam)/sqrt(K)
  const double* __restrict__ csqd = (const double*)(ws + WS_CSQ);

  double sc[8];
#pragma unroll
  for (int u = 0; u < 8; ++u) {
    const int n = cg + 8 * u;
    const double c_sq = csqd[n];
    const double dist_sq = z_sq + c_sq - 2.0 * zc[u];
    const double denom = (1.0 - z_sq) * (1.0 - c_sq);
    double arg = 1.0 + 2.0 * dist_sq / (denom + EPS);
    arg = fmax(arg, 1.0 + EPS);
    const double dist = log(arg + sqrt(arg * arg - 1.0));
    sc[u] = -dist * inv_tau + (double)lin[u] * lam_fac;
  }
  __syncthreads();  // all cqT/zt/slin reads done before s_exp overlay

  // per-thread max (n increasing -> strict '>' keeps lowest index)
  {
    double mx = sc[0];
    int am = cg;
#pragma unroll
    for (int u = 1; u < 8; ++u)
      if (sc[u] > mx) { mx = sc[u]; am = cg + 8 * u; }
    pmax[r][cg] = mx;
    parg[r][cg] = am;
  }
  __syncthreads();
  if (t < 32) {
    double m = pmax[t][0];
    int a = parg[t][0];
#pragma unroll
    for (int g = 1; g < 8; ++g) {
      const double v = pmax[t][g];
      const int aa = parg[t][g];
      if (v > m || (v == m && aa < a)) { m = v; a = aa; }
    }
    rowmax[t] = m;
    rowarg[t] = a;
  }
  __syncthreads();
  {
    const double m = rowmax[r];
    double ps = 0.0;
#pragma unroll
    for (int u = 0; u < 8; ++u) {
      const double e = exp(sc[u] - m);
      s_exp[r][cg + 8 * u] = e;
      ps += e;
    }
    pmax[r][cg] = ps;
  }
  __syncthreads();
  if (t < 32) {
    double s = 0.0;
#pragma unroll
    for (int g = 0; g < 8; ++g) s += pmax[t][g];
    rowinv[t] = 1.0 / s;
  }
  __syncthreads();
  for (int idx = t; idx < 2048; idx += 256) {
    const int b = idx >> 6, n = idx & 63;
    out[(size_t)(b0 + b) * 64 + n] = (float)(s_exp[b][n] * rowinv[b]);
  }
  if (t < 32) out[(size_t)B_TOT * 64 + b0 + t] = (float)rowarg[t];
}

extern "C" void kernel_launch(void* const* d_in, const int* in_sizes, int n_in,
                              void* d_out, int out_size, void* d_ws, size_t ws_size,
                              hipStream_t stream) {
  const float* z = (const float*)d_in[0];
  const float* feat = (const float*)d_in[1];
  const float* qzw = (const float*)d_in[2];
  const float* qzb = (const float*)d_in[3];
  const float* qfw = (const float*)d_in[4];
  const float* qfb = (const float*)d_in[5];
  const float* gamma = (const float*)d_in[6];
  const float* cq = (const float*)d_in[7];
  float* out = (float*)d_out;
  char* ws = (char*)d_ws;  // requires ws_size >= 6033408

  prep_s<<<dim3(256), dim3(256), 0, stream>>>(gamma, cq, ws);
  prep_pack<<<dim3(256), dim3(256), 0, stream>>>(qfw, cq, qzw, qzb, qfb, ws);
  gemm_kernel<<<dim3(B_TOT / 32), dim3(256), 0, stream>>>(z, feat, ws);
  tail_kernel<<<dim3(B_TOT / 32), dim3(256), 0, stream>>>(z, cq, ws, out);
}